// Round 2
// baseline (5644.196 us; speedup 1.0000x reference)
//
#include <hip/hip_runtime.h>
#include <hip/hip_bf16.h>

#define NN 20000
#define KK 16
#define DD 128
#define HH 256
#define IN3 384

typedef __hip_bfloat16 bf16;

__device__ __forceinline__ float b2f(bf16 x) { return __bfloat162float(x); }

template<bool F32>
__device__ __forceinline__ float ld(const void* p, size_t i) {
    if (F32) return ((const float*)p)[i];
    else     return b2f(((const bf16*)p)[i]);
}
template<bool F32>
__device__ __forceinline__ void st(void* p, size_t i, float v) {
    if (F32) ((float*)p)[i] = v;
    else     ((bf16*)p)[i] = __float2bfloat16(v);
}

__device__ __forceinline__ float gelu_tanh(float x) {
    const float c = 0.7978845608028654f;
    return 0.5f * x * (1.0f + tanhf(c * (x + 0.044715f * x * x * x)));
}
__device__ __forceinline__ float sigm(float x) { return 1.0f / (1.0f + __expf(-x)); }

// mask is all-ones. f32 1.0f -> bytes 00 00 80 3F -> u16[0]==0x0000.
// bf16 1.0 -> bytes 80 3F -> u16[0]==0x3F80.
__device__ __forceinline__ bool detect_f32(const void* mask) {
    return ((const unsigned short*)mask)[0] == 0;
}

template<bool F32>
__device__ __forceinline__ void pair_body(
    const void* __restrict__ local, const void* __restrict__ pair,
    const int* __restrict__ nbrs, const void* __restrict__ mask,
    const void* __restrict__ Wg1, const void* __restrict__ bg1,
    const void* __restrict__ Wv1, const void* __restrict__ bv1,
    const void* __restrict__ Wo1, const void* __restrict__ bo1,
    const void* __restrict__ gp, const void* __restrict__ bp,
    const void* __restrict__ Win, const void* __restrict__ Wout,
    void* __restrict__ d_out, float* __restrict__ inc_ws,
    float* __restrict__ outg_ws)
{
    __shared__ float xs[KK][IN3];
    __shared__ float hs[KK][HH];
    __shared__ float us[KK][DD];
    __shared__ float mv[KK][2];
    __shared__ float incp[2][DD];
    __shared__ int   nbr_s[KK];
    __shared__ float msk_s[KK];

    const int n = blockIdx.x;
    const int t = threadIdx.x;
    const size_t OUT_PAIR_OFS = (size_t)NN * DD;   // pair output follows local output

    if (t < KK) {
        int nb = nbrs[n * KK + t];
        int nbw = (nb < 0) ? nb + NN : nb;   // JAX negative-index wrap
        nbr_s[t] = nbw;
        float mk = ld<F32>(mask, nbw);
        msk_s[t] = (nb != -1 && mk > 0.0f) ? 1.0f : 0.0f;
    }
    __syncthreads();

    for (int idx = t; idx < KK * DD; idx += 256) {
        int k = idx >> 7, d = idx & 127;
        xs[k][d]          = ld<F32>(pair, ((size_t)n * KK + k) * DD + d);
        xs[k][DD + d]     = ld<F32>(local, (size_t)n * DD + d);
        xs[k][2 * DD + d] = ld<F32>(local, (size_t)nbr_s[k] * DD + d);
    }
    __syncthreads();

    // Phase A: thread t owns hidden unit j = t for all 16 k rows
    float ag[KK], av[KK];
#pragma unroll
    for (int k = 0; k < KK; k++) { ag[k] = 0.0f; av[k] = 0.0f; }
    for (int i = 0; i < IN3; i++) {
        float wg = ld<F32>(Wg1, (size_t)i * HH + t);
        float wv = ld<F32>(Wv1, (size_t)i * HH + t);
#pragma unroll
        for (int k = 0; k < KK; k++) {
            float xv = xs[k][i];
            ag[k] = fmaf(xv, wg, ag[k]);
            av[k] = fmaf(xv, wv, av[k]);
        }
    }
    {
        float bg = ld<F32>(bg1, t), bv = ld<F32>(bv1, t);
#pragma unroll
        for (int k = 0; k < KK; k++)
            hs[k][t] = gelu_tanh(ag[k] + bg) * (av[k] + bv);
    }
    __syncthreads();

    // Phase B: output projection
    const int d = t & 127;
    const int kh = t >> 7;
    float au[8];
#pragma unroll
    for (int kk = 0; kk < 8; kk++) au[kk] = 0.0f;
    for (int j = 0; j < HH; j++) {
        float w = ld<F32>(Wo1, (size_t)j * DD + d);
#pragma unroll
        for (int kk = 0; kk < 8; kk++)
            au[kk] = fmaf(hs[kh * 8 + kk][j], w, au[kk]);
    }
    {
        float bo = ld<F32>(bo1, d);
#pragma unroll
        for (int kk = 0; kk < 8; kk++)
            us[kh * 8 + kk][d] = au[kk] + bo;
    }
    __syncthreads();

    // LayerNorm stats (16 lanes per k row)
    {
        int k = t >> 4, dd = t & 15;
        float s = 0.0f, s2 = 0.0f;
#pragma unroll
        for (int r = 0; r < 8; r++) {
            float v = us[k][dd + 16 * r];
            s += v; s2 += v * v;
        }
#pragma unroll
        for (int off = 1; off < 16; off <<= 1) {
            s += __shfl_xor(s, off, 64);
            s2 += __shfl_xor(s2, off, 64);
        }
        if (dd == 0) {
            float mean = s * (1.0f / DD);
            float var = s2 * (1.0f / DD) - mean * mean;
            mv[k][0] = mean;
            mv[k][1] = rsqrtf(var + 1e-5f);
        }
    }
    __syncthreads();

    // Phase C: LN + residual write
    float pu[8];
    {
        float gpd = ld<F32>(gp, d), bpd = ld<F32>(bp, d);
#pragma unroll
        for (int kk = 0; kk < 8; kk++) {
            int k = kh * 8 + kk;
            float p = (us[k][d] - mv[k][0]) * mv[k][1] * gpd + bpd;
            pu[kk] = p;
            st<F32>(d_out, OUT_PAIR_OFS + ((size_t)n * KK + k) * DD + d,
                    xs[k][d] + p);
        }
    }

    // Gates
    float ain[8], aot[8];
#pragma unroll
    for (int kk = 0; kk < 8; kk++) { ain[kk] = 0.0f; aot[kk] = 0.0f; }
    for (int i = 0; i < DD; i++) {
        float wi = ld<F32>(Win, (size_t)i * DD + d);
        float wo = ld<F32>(Wout, (size_t)i * DD + d);
#pragma unroll
        for (int kk = 0; kk < 8; kk++) {
            float pv = xs[kh * 8 + kk][i];
            ain[kk] = fmaf(pv, wi, ain[kk]);
            aot[kk] = fmaf(pv, wo, aot[kk]);
        }
    }
    float incpart = 0.0f;
#pragma unroll
    for (int kk = 0; kk < 8; kk++) {
        int k = kh * 8 + kk;
        if (msk_s[k] != 0.0f) {
            float p = pu[kk];
            incpart += sigm(ain[kk]) * p;
            atomicAdd(&outg_ws[(size_t)nbr_s[k] * DD + d], sigm(aot[kk]) * p);
        }
    }
    incp[kh][d] = incpart;
    __syncthreads();
    if (t < DD)
        inc_ws[(size_t)n * DD + t] = incp[0][t] + incp[1][t];
}

__global__ __launch_bounds__(256) void k_pair(
    const void* __restrict__ local, const void* __restrict__ pair,
    const int* __restrict__ nbrs, const void* __restrict__ mask,
    const void* __restrict__ Wg1, const void* __restrict__ bg1,
    const void* __restrict__ Wv1, const void* __restrict__ bv1,
    const void* __restrict__ Wo1, const void* __restrict__ bo1,
    const void* __restrict__ gp, const void* __restrict__ bp,
    const void* __restrict__ Win, const void* __restrict__ Wout,
    void* __restrict__ d_out, float* __restrict__ inc_ws,
    float* __restrict__ outg_ws)
{
    if (detect_f32(mask))
        pair_body<true>(local, pair, nbrs, mask, Wg1, bg1, Wv1, bv1, Wo1, bo1,
                        gp, bp, Win, Wout, d_out, inc_ws, outg_ws);
    else
        pair_body<false>(local, pair, nbrs, mask, Wg1, bg1, Wv1, bv1, Wo1, bo1,
                         gp, bp, Win, Wout, d_out, inc_ws, outg_ws);
}

template<bool F32>
__device__ __forceinline__ void local_body(
    const void* __restrict__ local, const float* __restrict__ inc_ws,
    const float* __restrict__ outg_ws,
    const void* __restrict__ Wg2, const void* __restrict__ bg2,
    const void* __restrict__ Wv2, const void* __restrict__ bv2,
    const void* __restrict__ Wo2, const void* __restrict__ bo2,
    const void* __restrict__ gl, const void* __restrict__ bl,
    void* __restrict__ out_local)
{
    __shared__ float xs[16][IN3];
    __shared__ float hs[16][HH];
    __shared__ float us[16][DD];
    __shared__ float mv[16][2];

    const int n0 = blockIdx.x * 16;
    const int t = threadIdx.x;

    for (int idx = t; idx < 16 * DD; idx += 256) {
        int r = idx >> 7, d2 = idx & 127;
        size_t n = n0 + r;
        xs[r][d2]          = ld<F32>(local, n * DD + d2);
        xs[r][DD + d2]     = inc_ws[n * DD + d2];
        xs[r][2 * DD + d2] = outg_ws[n * DD + d2];
    }
    __syncthreads();

    float ag[16], av[16];
#pragma unroll
    for (int k = 0; k < 16; k++) { ag[k] = 0.0f; av[k] = 0.0f; }
    for (int i = 0; i < IN3; i++) {
        float wg = ld<F32>(Wg2, (size_t)i * HH + t);
        float wv = ld<F32>(Wv2, (size_t)i * HH + t);
#pragma unroll
        for (int k = 0; k < 16; k++) {
            float xv = xs[k][i];
            ag[k] = fmaf(xv, wg, ag[k]);
            av[k] = fmaf(xv, wv, av[k]);
        }
    }
    {
        float bg = ld<F32>(bg2, t), bv = ld<F32>(bv2, t);
#pragma unroll
        for (int k = 0; k < 16; k++)
            hs[k][t] = gelu_tanh(ag[k] + bg) * (av[k] + bv);
    }
    __syncthreads();

    const int d = t & 127;
    const int kh = t >> 7;
    float au[8];
#pragma unroll
    for (int kk = 0; kk < 8; kk++) au[kk] = 0.0f;
    for (int j = 0; j < HH; j++) {
        float w = ld<F32>(Wo2, (size_t)j * DD + d);
#pragma unroll
        for (int kk = 0; kk < 8; kk++)
            au[kk] = fmaf(hs[kh * 8 + kk][j], w, au[kk]);
    }
    {
        float bo = ld<F32>(bo2, d);
#pragma unroll
        for (int kk = 0; kk < 8; kk++)
            us[kh * 8 + kk][d] = au[kk] + bo;
    }
    __syncthreads();

    {
        int k = t >> 4, dd = t & 15;
        float s = 0.0f, s2 = 0.0f;
#pragma unroll
        for (int r = 0; r < 8; r++) {
            float v = us[k][dd + 16 * r];
            s += v; s2 += v * v;
        }
#pragma unroll
        for (int off = 1; off < 16; off <<= 1) {
            s += __shfl_xor(s, off, 64);
            s2 += __shfl_xor(s2, off, 64);
        }
        if (dd == 0) {
            float mean = s * (1.0f / DD);
            float var = s2 * (1.0f / DD) - mean * mean;
            mv[k][0] = mean;
            mv[k][1] = rsqrtf(var + 1e-5f);
        }
    }
    __syncthreads();

    {
        float gld = ld<F32>(gl, d), bld = ld<F32>(bl, d);
#pragma unroll
        for (int kk = 0; kk < 8; kk++) {
            int r = kh * 8 + kk;
            float p = (us[r][d] - mv[r][0]) * mv[r][1] * gld + bld;
            st<F32>(out_local, (size_t)(n0 + r) * DD + d, xs[r][d] + p);
        }
    }
}

__global__ __launch_bounds__(256) void k_local(
    const void* __restrict__ local, const float* __restrict__ inc_ws,
    const float* __restrict__ outg_ws, const void* __restrict__ mask,
    const void* __restrict__ Wg2, const void* __restrict__ bg2,
    const void* __restrict__ Wv2, const void* __restrict__ bv2,
    const void* __restrict__ Wo2, const void* __restrict__ bo2,
    const void* __restrict__ gl, const void* __restrict__ bl,
    void* __restrict__ out_local)
{
    if (detect_f32(mask))
        local_body<true>(local, inc_ws, outg_ws, Wg2, bg2, Wv2, bv2,
                         Wo2, bo2, gl, bl, out_local);
    else
        local_body<false>(local, inc_ws, outg_ws, Wg2, bg2, Wv2, bv2,
                          Wo2, bo2, gl, bl, out_local);
}

extern "C" void kernel_launch(void* const* d_in, const int* in_sizes, int n_in,
                              void* d_out, int out_size, void* d_ws, size_t ws_size,
                              hipStream_t stream) {
    const void* local = d_in[0];
    const void* pair  = d_in[1];
    const int*  nbrs  = (const int*)d_in[2];
    const void* mask  = d_in[3];
    const void* Wg1 = d_in[4];
    const void* bg1 = d_in[5];
    const void* Wv1 = d_in[6];
    const void* bv1 = d_in[7];
    const void* Wo1 = d_in[8];
    const void* bo1 = d_in[9];
    const void* gp  = d_in[10];
    const void* bp  = d_in[11];
    const void* Win = d_in[12];
    const void* Wout= d_in[13];
    const void* Wg2 = d_in[14];
    const void* bg2 = d_in[15];
    const void* Wv2 = d_in[16];
    const void* bv2 = d_in[17];
    const void* Wo2 = d_in[18];
    const void* bo2 = d_in[19];
    const void* gl  = d_in[20];
    const void* bl  = d_in[21];

    float* inc_ws  = (float*)d_ws;
    float* outg_ws = inc_ws + (size_t)NN * DD;

    hipMemsetAsync(outg_ws, 0, (size_t)NN * DD * sizeof(float), stream);

    k_pair<<<NN, 256, 0, stream>>>(local, pair, nbrs, mask,
                                   Wg1, bg1, Wv1, bv1, Wo1, bo1, gp, bp,
                                   Win, Wout, d_out, inc_ws, outg_ws);
    k_local<<<NN / 16, 256, 0, stream>>>(local, inc_ws, outg_ws, mask,
                                         Wg2, bg2, Wv2, bv2, Wo2, bo2, gl, bl,
                                         d_out);
}

// Round 3
// 1516.714 us; speedup vs baseline: 3.7213x; 3.7213x over previous
//
#include <hip/hip_runtime.h>
#include <hip/hip_bf16.h>

#define NN 20000
#define KK 16
#define DD 128
#define HH 256
#define IN3 384

typedef __hip_bfloat16 bf16;
typedef __bf16 bf8v __attribute__((ext_vector_type(8)));
typedef float f4v __attribute__((ext_vector_type(4)));

#define MFMA16(a, b, c) __builtin_amdgcn_mfma_f32_16x16x32_bf16((a), (b), (c), 0, 0, 0)

// bf16 transposed-weight layout in ws (element offsets):
// Wt1  [512][384] : rows 0-255 Wg1^T, 256-511 Wv1^T
// Wto1 [128][256] : Wo1^T
// Wtg  [256][128] : rows 0-127 Win^T, 128-255 Wout^T
// Wt2  [512][384] : Wg2^T / Wv2^T
// Wto2 [128][256] : Wo2^T
#define WT1_OFS  0
#define WTO1_OFS 196608
#define WTG_OFS  229376
#define WT2_OFS  262144
#define WTO2_OFS 458752
#define WT_TOTAL 491520

__device__ __forceinline__ float gelu_tanh(float x) {
    const float c = 0.7978845608028654f;
    return 0.5f * x * (1.0f + tanhf(c * (x + 0.044715f * x * x * x)));
}
__device__ __forceinline__ float sigm(float x) { return 1.0f / (1.0f + __expf(-x)); }

__global__ __launch_bounds__(256) void k_prep(
    const float* __restrict__ Wg1, const float* __restrict__ Wv1,
    const float* __restrict__ Wo1,
    const float* __restrict__ Win, const float* __restrict__ Wout,
    const float* __restrict__ Wg2, const float* __restrict__ Wv2,
    const float* __restrict__ Wo2, bf16* __restrict__ wt)
{
    int idx = blockIdx.x * 256 + threadIdx.x;
    if (idx >= WT_TOTAL) return;
    float v;
    if (idx < WTO1_OFS) {
        int i = idx, n = i / IN3, k = i % IN3;
        v = (n < HH) ? Wg1[(size_t)k * HH + n] : Wv1[(size_t)k * HH + (n - HH)];
    } else if (idx < WTG_OFS) {
        int i = idx - WTO1_OFS, n = i / HH, k = i % HH;
        v = Wo1[(size_t)k * DD + n];
    } else if (idx < WT2_OFS) {
        int i = idx - WTG_OFS, n = i / DD, k = i % DD;
        v = (n < DD) ? Win[(size_t)k * DD + n] : Wout[(size_t)k * DD + (n - DD)];
    } else if (idx < WTO2_OFS) {
        int i = idx - WT2_OFS, n = i / IN3, k = i % IN3;
        v = (n < HH) ? Wg2[(size_t)k * HH + n] : Wv2[(size_t)k * HH + (n - HH)];
    } else {
        int i = idx - WTO2_OFS, n = i / HH, k = i % HH;
        v = Wo2[(size_t)k * DD + n];
    }
    wt[idx] = __float2bfloat16(v);
}

// One block = 4 nodes (M = 64 rows of 16 neighbours each). 256 threads = 4 waves.
// Wave w owns: GEMM1 mtiles 0-3 x ntile-pairs (g: (w*4+i)*16, v: 256+(w*4+i)*16);
// GEMM2/gates: mtile w (== node w), all ntiles.  MFMA 16x16x32 bf16 throughout.
__global__ __launch_bounds__(256, 1) void k_pair(
    const float* __restrict__ localp, const float* __restrict__ pairp,
    const int* __restrict__ nbrs, const float* __restrict__ mask,
    const bf16* __restrict__ wt,
    const float* __restrict__ bg1, const float* __restrict__ bv1,
    const float* __restrict__ bo1,
    const float* __restrict__ gp, const float* __restrict__ bp,
    float* __restrict__ out, float* __restrict__ inc_ws,
    float* __restrict__ outg_ws)
{
    __shared__ bf16 xs[64][392];           // 50176 B  (A: [pair|local|local_nbr])
    __shared__ char hs_raw[64 * 264 * 2];  // 33792 B  (h bf16; later pu f32 [64][132])
    __shared__ int   nbr_s[4][16];
    __shared__ float msk_s[4][16];
    bf16 (*hs)[264] = (bf16 (*)[264])hs_raw;
    float (*pu)[132] = (float (*)[132])hs_raw;

    const int t = threadIdx.x;
    const int n0 = blockIdx.x * 4;
    const int l = t & 63, w = t >> 6;
    const int lg = l & 15, lq = l >> 4;

    if (t < 64) {
        int node = t >> 4, k = t & 15;
        int nb = nbrs[(n0 + node) * KK + k];
        int nbw = (nb < 0) ? nb + NN : nb;     // JAX negative-index wrap
        nbr_s[node][k] = nbw;
        msk_s[node][k] = (nb != -1 && mask[nbw] > 0.0f) ? 1.0f : 0.0f;
    }
    __syncthreads();

    // Stage x rows (f32 -> bf16)
    for (int idx = t; idx < 64 * 96; idx += 256) {
        int row = idx / 96, g = idx % 96, c = g * 4;
        int node = row >> 4, k = row & 15;
        float4 v;
        if (c < 128)      v = *(const float4*)&pairp[((size_t)(n0 + node) * KK + k) * DD + c];
        else if (c < 256) v = *(const float4*)&localp[(size_t)(n0 + node) * DD + (c - 128)];
        else              v = *(const float4*)&localp[(size_t)nbr_s[node][k] * DD + (c - 256)];
        bf16* dst = &xs[row][c];
        dst[0] = __float2bfloat16(v.x); dst[1] = __float2bfloat16(v.y);
        dst[2] = __float2bfloat16(v.z); dst[3] = __float2bfloat16(v.w);
    }
    __syncthreads();

    // ---- GEMM1: [64x384] @ Wt1^T -> g|v [64x512] ----
    f4v acc[4][8];
#pragma unroll
    for (int i = 0; i < 4; i++)
#pragma unroll
        for (int j = 0; j < 8; j++) acc[i][j] = (f4v){0.f, 0.f, 0.f, 0.f};

    const bf16* Wt1 = wt + WT1_OFS;
    for (int ko = 0; ko < 12; ko++) {
        bf8v A[4];
#pragma unroll
        for (int mt = 0; mt < 4; mt++)
            A[mt] = *(const bf8v*)&xs[mt * 16 + lg][ko * 32 + lq * 8];
#pragma unroll
        for (int ntl = 0; ntl < 8; ntl++) {
            int nrow = (ntl < 4) ? (w * 4 + ntl) * 16 + lg
                                 : 256 + (w * 4 + (ntl - 4)) * 16 + lg;
            bf8v B = *(const bf8v*)(Wt1 + (size_t)nrow * IN3 + ko * 32 + lq * 8);
#pragma unroll
            for (int mt = 0; mt < 4; mt++)
                acc[mt][ntl] = MFMA16(A[mt], B, acc[mt][ntl]);
        }
    }
    // epilogue: h = gelu(g+bg)*(v+bv) -> hs
#pragma unroll
    for (int ntl = 0; ntl < 4; ntl++) {
        int colg = (w * 4 + ntl) * 16 + lg;
        float bg = bg1[colg], bv = bv1[colg];
#pragma unroll
        for (int mt = 0; mt < 4; mt++)
#pragma unroll
            for (int r = 0; r < 4; r++) {
                float g = acc[mt][ntl][r] + bg;
                float vv = acc[mt][ntl + 4][r] + bv;
                hs[mt * 16 + lq * 4 + r][colg] = __float2bfloat16(gelu_tanh(g) * vv);
            }
    }
    __syncthreads();

    // ---- GEMM2: h[64x256] @ Wo1 -> u [64x128]; wave w = mtile w (node w) ----
    f4v acc2[8];
#pragma unroll
    for (int j = 0; j < 8; j++) acc2[j] = (f4v){0.f, 0.f, 0.f, 0.f};
    const bf16* Wto1 = wt + WTO1_OFS;
    for (int ko = 0; ko < 8; ko++) {
        bf8v A = *(const bf8v*)&hs[w * 16 + lg][ko * 32 + lq * 8];
#pragma unroll
        for (int nt = 0; nt < 8; nt++) {
            bf8v B = *(const bf8v*)(Wto1 + (size_t)(nt * 16 + lg) * HH + ko * 32 + lq * 8);
            acc2[nt] = MFMA16(A, B, acc2[nt]);
        }
    }
    // bias + LN stats (rows of node w live in this wave)
    float s[4] = {0, 0, 0, 0}, s2[4] = {0, 0, 0, 0};
#pragma unroll
    for (int nt = 0; nt < 8; nt++) {
        float bo = bo1[nt * 16 + lg];
#pragma unroll
        for (int r = 0; r < 4; r++) {
            float u = acc2[nt][r] + bo;
            acc2[nt][r] = u;
            s[r] += u; s2[r] += u * u;
        }
    }
#pragma unroll
    for (int off = 1; off < 16; off <<= 1)
#pragma unroll
        for (int r = 0; r < 4; r++) {
            s[r]  += __shfl_xor(s[r], off, 64);
            s2[r] += __shfl_xor(s2[r], off, 64);
        }
    float mean[4], rstd[4];
#pragma unroll
    for (int r = 0; r < 4; r++) {
        mean[r] = s[r] * (1.0f / DD);
        float var = s2[r] * (1.0f / DD) - mean[r] * mean[r];
        rstd[r] = rsqrtf(var + 1e-5f);
    }
    __syncthreads();   // all waves done reading hs -> safe to overwrite with pu

    const size_t OUT_PAIR_OFS = (size_t)NN * DD;
#pragma unroll
    for (int nt = 0; nt < 8; nt++) {
        int col = nt * 16 + lg;
        float gpd = gp[col], bpd = bp[col];
#pragma unroll
        for (int r = 0; r < 4; r++) {
            int row = w * 16 + lq * 4 + r;
            float p = (acc2[nt][r] - mean[r]) * rstd[r] * gpd + bpd;
            pu[row][col] = p;
            size_t gidx = ((size_t)(n0 + w) * KK + (row & 15)) * DD + col;
            out[OUT_PAIR_OFS + gidx] = pairp[gidx] + p;
        }
    }

    // ---- Gates: pair[16x128] @ [Win|Wout] -> [16x256]; wave w = node w ----
    f4v acc3[16];
#pragma unroll
    for (int j = 0; j < 16; j++) acc3[j] = (f4v){0.f, 0.f, 0.f, 0.f};
    const bf16* Wtg = wt + WTG_OFS;
    for (int ko = 0; ko < 4; ko++) {
        bf8v A = *(const bf8v*)&xs[w * 16 + lg][ko * 32 + lq * 8];  // pair cols
#pragma unroll
        for (int nt = 0; nt < 16; nt++) {
            bf8v B = *(const bf8v*)(Wtg + (size_t)(nt * 16 + lg) * DD + ko * 32 + lq * 8);
            acc3[nt] = MFMA16(A, B, acc3[nt]);
        }
    }
    // incoming: sum_k sigm(gin)*pu*mask  (reduce across lq groups)
#pragma unroll
    for (int nt = 0; nt < 8; nt++) {
        int col = nt * 16 + lg;
        float sl = 0.f;
#pragma unroll
        for (int r = 0; r < 4; r++) {
            int k = lq * 4 + r;
            sl += sigm(acc3[nt][r]) * pu[w * 16 + k][col] * msk_s[w][k];
        }
        sl += __shfl_xor(sl, 16, 64);
        sl += __shfl_xor(sl, 32, 64);
        if (l < 16)
            inc_ws[(size_t)(n0 + w) * DD + nt * 16 + l] = sl;
    }
    // outgoing: scatter-add sigm(gout)*pu*mask to neighbour rows
#pragma unroll
    for (int nt = 0; nt < 8; nt++) {
        int col = nt * 16 + lg;
#pragma unroll
        for (int r = 0; r < 4; r++) {
            int k = lq * 4 + r;
            if (msk_s[w][k] != 0.0f) {
                float o = sigm(acc3[nt + 8][r]) * pu[w * 16 + k][col];
                atomicAdd(&outg_ws[(size_t)nbr_s[w][k] * DD + col], o);
            }
        }
    }
}

// One block = 64 nodes (M = 64 rows). Same GEMM skeleton, no gates.
__global__ __launch_bounds__(256, 1) void k_local(
    const float* __restrict__ localp, const float* __restrict__ inc_ws,
    const float* __restrict__ outg_ws, const bf16* __restrict__ wt,
    const float* __restrict__ bg2, const float* __restrict__ bv2,
    const float* __restrict__ bo2,
    const float* __restrict__ gl, const float* __restrict__ bl,
    float* __restrict__ out)
{
    __shared__ bf16 xs[64][392];
    __shared__ char hs_raw[64 * 264 * 2];
    bf16 (*hs)[264] = (bf16 (*)[264])hs_raw;

    const int t = threadIdx.x;
    const int n0 = blockIdx.x * 64;
    const int l = t & 63, w = t >> 6;
    const int lg = l & 15, lq = l >> 4;

    for (int idx = t; idx < 64 * 96; idx += 256) {
        int row = idx / 96, g = idx % 96, c = g * 4;
        int node = n0 + row;
        float4 v = {0.f, 0.f, 0.f, 0.f};
        if (node < NN) {
            if (c < 128)      v = *(const float4*)&localp[(size_t)node * DD + c];
            else if (c < 256) v = *(const float4*)&inc_ws[(size_t)node * DD + (c - 128)];
            else              v = *(const float4*)&outg_ws[(size_t)node * DD + (c - 256)];
        }
        bf16* dst = &xs[row][c];
        dst[0] = __float2bfloat16(v.x); dst[1] = __float2bfloat16(v.y);
        dst[2] = __float2bfloat16(v.z); dst[3] = __float2bfloat16(v.w);
    }
    __syncthreads();

    f4v acc[4][8];
#pragma unroll
    for (int i = 0; i < 4; i++)
#pragma unroll
        for (int j = 0; j < 8; j++) acc[i][j] = (f4v){0.f, 0.f, 0.f, 0.f};

    const bf16* Wt2 = wt + WT2_OFS;
    for (int ko = 0; ko < 12; ko++) {
        bf8v A[4];
#pragma unroll
        for (int mt = 0; mt < 4; mt++)
            A[mt] = *(const bf8v*)&xs[mt * 16 + lg][ko * 32 + lq * 8];
#pragma unroll
        for (int ntl = 0; ntl < 8; ntl++) {
            int nrow = (ntl < 4) ? (w * 4 + ntl) * 16 + lg
                                 : 256 + (w * 4 + (ntl - 4)) * 16 + lg;
            bf8v B = *(const bf8v*)(Wt2 + (size_t)nrow * IN3 + ko * 32 + lq * 8);
#pragma unroll
            for (int mt = 0; mt < 4; mt++)
                acc[mt][ntl] = MFMA16(A[mt], B, acc[mt][ntl]);
        }
    }
#pragma unroll
    for (int ntl = 0; ntl < 4; ntl++) {
        int colg = (w * 4 + ntl) * 16 + lg;
        float bg = bg2[colg], bv = bv2[colg];
#pragma unroll
        for (int mt = 0; mt < 4; mt++)
#pragma unroll
            for (int r = 0; r < 4; r++) {
                float g = acc[mt][ntl][r] + bg;
                float vv = acc[mt][ntl + 4][r] + bv;
                hs[mt * 16 + lq * 4 + r][colg] = __float2bfloat16(gelu_tanh(g) * vv);
            }
    }
    __syncthreads();

    f4v acc2[8];
#pragma unroll
    for (int j = 0; j < 8; j++) acc2[j] = (f4v){0.f, 0.f, 0.f, 0.f};
    const bf16* Wto2 = wt + WTO2_OFS;
    for (int ko = 0; ko < 8; ko++) {
        bf8v A = *(const bf8v*)&hs[w * 16 + lg][ko * 32 + lq * 8];
#pragma unroll
        for (int nt = 0; nt < 8; nt++) {
            bf8v B = *(const bf8v*)(Wto2 + (size_t)(nt * 16 + lg) * HH + ko * 32 + lq * 8);
            acc2[nt] = MFMA16(A, B, acc2[nt]);
        }
    }
    float s[4] = {0, 0, 0, 0}, s2[4] = {0, 0, 0, 0};
#pragma unroll
    for (int nt = 0; nt < 8; nt++) {
        float bo = bo2[nt * 16 + lg];
#pragma unroll
        for (int r = 0; r < 4; r++) {
            float u = acc2[nt][r] + bo;
            acc2[nt][r] = u;
            s[r] += u; s2[r] += u * u;
        }
    }
#pragma unroll
    for (int off = 1; off < 16; off <<= 1)
#pragma unroll
        for (int r = 0; r < 4; r++) {
            s[r]  += __shfl_xor(s[r], off, 64);
            s2[r] += __shfl_xor(s2[r], off, 64);
        }
    float mean[4], rstd[4];
#pragma unroll
    for (int r = 0; r < 4; r++) {
        mean[r] = s[r] * (1.0f / DD);
        float var = s2[r] * (1.0f / DD) - mean[r] * mean[r];
        rstd[r] = rsqrtf(var + 1e-5f);
    }
#pragma unroll
    for (int nt = 0; nt < 8; nt++) {
        int col = nt * 16 + lg;
        float gld = gl[col], bld = bl[col];
#pragma unroll
        for (int r = 0; r < 4; r++) {
            int row = w * 16 + lq * 4 + r;
            int node = n0 + row;
            if (node < NN) {
                float p = (acc2[nt][r] - mean[r]) * rstd[r] * gld + bld;
                out[(size_t)node * DD + col] = localp[(size_t)node * DD + col] + p;
            }
        }
    }
}

extern "C" void kernel_launch(void* const* d_in, const int* in_sizes, int n_in,
                              void* d_out, int out_size, void* d_ws, size_t ws_size,
                              hipStream_t stream) {
    const float* local = (const float*)d_in[0];
    const float* pair  = (const float*)d_in[1];
    const int*   nbrs  = (const int*)d_in[2];
    const float* mask  = (const float*)d_in[3];
    const float* Wg1 = (const float*)d_in[4];
    const float* bg1 = (const float*)d_in[5];
    const float* Wv1 = (const float*)d_in[6];
    const float* bv1 = (const float*)d_in[7];
    const float* Wo1 = (const float*)d_in[8];
    const float* bo1 = (const float*)d_in[9];
    const float* gp  = (const float*)d_in[10];
    const float* bp  = (const float*)d_in[11];
    const float* Win = (const float*)d_in[12];
    const float* Wout= (const float*)d_in[13];
    const float* Wg2 = (const float*)d_in[14];
    const float* bg2 = (const float*)d_in[15];
    const float* Wv2 = (const float*)d_in[16];
    const float* bv2 = (const float*)d_in[17];
    const float* Wo2 = (const float*)d_in[18];
    const float* bo2 = (const float*)d_in[19];
    const float* gl  = (const float*)d_in[20];
    const float* bl  = (const float*)d_in[21];

    float* out = (float*)d_out;
    float* inc_ws  = (float*)d_ws;
    float* outg_ws = inc_ws + (size_t)NN * DD;
    bf16*  wt      = (bf16*)(outg_ws + (size_t)NN * DD);

    hipMemsetAsync(outg_ws, 0, (size_t)NN * DD * sizeof(float), stream);
    k_prep<<<(WT_TOTAL + 255) / 256, 256, 0, stream>>>(
        Wg1, Wv1, Wo1, Win, Wout, Wg2, Wv2, Wo2, wt);
    k_pair<<<NN / 4, 256, 0, stream>>>(local, pair, nbrs, mask, wt,
                                       bg1, bv1, bo1, gp, bp,
                                       out, inc_ws, outg_ws);
    k_local<<<(NN + 63) / 64, 256, 0, stream>>>(local, inc_ws, outg_ws, wt,
                                                bg2, bv2, bo2, gl, bl, out);
}

// Round 4
// 1238.168 us; speedup vs baseline: 4.5585x; 1.2250x over previous
//
#include <hip/hip_runtime.h>
#include <hip/hip_bf16.h>

#define NN 20000
#define KK 16
#define DD 128
#define HH 256
#define IN3 384

typedef __hip_bfloat16 bf16;
typedef __bf16 bf8v __attribute__((ext_vector_type(8)));
typedef float f4v __attribute__((ext_vector_type(4)));

#define MFMA16(a, b, c) __builtin_amdgcn_mfma_f32_16x16x32_bf16((a), (b), (c), 0, 0, 0)

// bf16 transposed-weight layout in ws (element offsets):
// Wt1  [512][384] : rows 0-255 Wg1^T, 256-511 Wv1^T
// Wto1 [128][256] : Wo1^T
// Wtg  [256][128] : rows 0-127 Win^T, 128-255 Wout^T
// Wt2  [512][384] : Wg2^T / Wv2^T
// Wto2 [128][256] : Wo2^T
#define WT1_OFS  0
#define WTO1_OFS 196608
#define WTG_OFS  229376
#define WT2_OFS  262144
#define WTO2_OFS 458752
#define WT_TOTAL 491520

// gelu(x) = 0.5x(1+tanh(c(x+0.044715x^3))); tanh via expf, branchless & safe
__device__ __forceinline__ float gelu_tanh(float x) {
    const float c = 0.7978845608028654f;
    float y = c * (x + 0.044715f * x * x * x);
    float e = __expf(-2.0f * fabsf(y));          // in (0,1], no overflow
    float th = (1.0f - e) / (1.0f + e);          // |tanh|
    th = copysignf(th, y);
    return 0.5f * x * (1.0f + th);
}
__device__ __forceinline__ float sigm(float x) { return 1.0f / (1.0f + __expf(-x)); }

__global__ __launch_bounds__(256) void k_prep(
    const float* __restrict__ Wg1, const float* __restrict__ Wv1,
    const float* __restrict__ Wo1,
    const float* __restrict__ Win, const float* __restrict__ Wout,
    const float* __restrict__ Wg2, const float* __restrict__ Wv2,
    const float* __restrict__ Wo2, bf16* __restrict__ wt)
{
    int idx = blockIdx.x * 256 + threadIdx.x;
    if (idx >= WT_TOTAL) return;
    float v;
    if (idx < WTO1_OFS) {
        int i = idx, n = i / IN3, k = i % IN3;
        v = (n < HH) ? Wg1[(size_t)k * HH + n] : Wv1[(size_t)k * HH + (n - HH)];
    } else if (idx < WTG_OFS) {
        int i = idx - WTO1_OFS, n = i / HH, k = i % HH;
        v = Wo1[(size_t)k * DD + n];
    } else if (idx < WT2_OFS) {
        int i = idx - WTG_OFS, n = i / DD, k = i % DD;
        v = (n < DD) ? Win[(size_t)k * DD + n] : Wout[(size_t)k * DD + (n - DD)];
    } else if (idx < WTO2_OFS) {
        int i = idx - WT2_OFS, n = i / IN3, k = i % IN3;
        v = (n < HH) ? Wg2[(size_t)k * HH + n] : Wv2[(size_t)k * HH + (n - HH)];
    } else {
        int i = idx - WTO2_OFS, n = i / HH, k = i % HH;
        v = Wo2[(size_t)k * DD + n];
    }
    wt[idx] = __float2bfloat16(v);
}

// One block = 2 nodes (M = 32 rows). 256 threads = 4 waves. LDS ~42.8 KB -> 3 blocks/CU.
// GEMM1: wave w owns ntile pairs (g:(w*4+i)*16, v:256+(w*4+i)*16), both mtiles.
// GEMM2/gates: wave (m=w&1, nh=w>>1) -> node m, column-half nh.
__global__ __launch_bounds__(256, 3) void k_pair(
    const float* __restrict__ localp, const float* __restrict__ pairp,
    const int* __restrict__ nbrs, const float* __restrict__ mask,
    const bf16* __restrict__ wt,
    const float* __restrict__ bg1, const float* __restrict__ bv1,
    const float* __restrict__ bo1,
    const float* __restrict__ gp, const float* __restrict__ bp,
    float* __restrict__ out, float* __restrict__ inc_ws,
    float* __restrict__ outg_ws)
{
    __shared__ bf16 xs[32][392];           // 25088 B  (A: [pair|local|local_nbr])
    __shared__ char hs_raw[32 * 264 * 2];  // 16896 B  (h bf16; later pu f32 [32][132])
    __shared__ float lnp[2][32][2];        // 512 B: LN partials [col-half][row][{s,s2}]
    __shared__ int   nbr_s[32];
    __shared__ float msk_s[32];
    bf16 (*hs)[264] = (bf16 (*)[264])hs_raw;
    float (*pu)[132] = (float (*)[132])hs_raw;

    const int t = threadIdx.x;
    const int n0 = blockIdx.x * 2;
    const int l = t & 63, w = t >> 6;
    const int lg = l & 15, lq = l >> 4;
    const int m = w & 1, nh = w >> 1;

    if (t < 32) {
        int node = t >> 4, k = t & 15;
        int nb = nbrs[(n0 + node) * KK + k];
        int nbw = (nb < 0) ? nb + NN : nb;     // JAX negative-index wrap
        nbr_s[t] = nbw;
        msk_s[t] = (nb != -1 && mask[nbw] > 0.0f) ? 1.0f : 0.0f;
    }
    __syncthreads();

    // Stage x rows (f32 -> bf16)
    for (int idx = t; idx < 32 * 96; idx += 256) {
        int row = idx / 96, g = idx % 96, c = g * 4;
        int node = row >> 4, k = row & 15;
        float4 v;
        if (c < 128)      v = *(const float4*)&pairp[((size_t)(n0 + node) * KK + k) * DD + c];
        else if (c < 256) v = *(const float4*)&localp[(size_t)(n0 + node) * DD + (c - 128)];
        else              v = *(const float4*)&localp[(size_t)nbr_s[row] * DD + (c - 256)];
        bf16* dst = &xs[row][c];
        dst[0] = __float2bfloat16(v.x); dst[1] = __float2bfloat16(v.y);
        dst[2] = __float2bfloat16(v.z); dst[3] = __float2bfloat16(v.w);
    }
    __syncthreads();

    // ---- GEMM1: [32x384] @ Wt1^T -> g|v [32x512] ----
    f4v acc[2][8];
#pragma unroll
    for (int i = 0; i < 2; i++)
#pragma unroll
        for (int j = 0; j < 8; j++) acc[i][j] = (f4v){0.f, 0.f, 0.f, 0.f};

    const bf16* Wt1 = wt + WT1_OFS;
    for (int ko = 0; ko < 12; ko++) {
        bf8v A0 = *(const bf8v*)&xs[lg][ko * 32 + lq * 8];
        bf8v A1 = *(const bf8v*)&xs[16 + lg][ko * 32 + lq * 8];
#pragma unroll
        for (int ntl = 0; ntl < 8; ntl++) {
            int nrow = (ntl < 4) ? (w * 4 + ntl) * 16 + lg
                                 : 256 + (w * 4 + (ntl - 4)) * 16 + lg;
            bf8v B = *(const bf8v*)(Wt1 + (size_t)nrow * IN3 + ko * 32 + lq * 8);
            acc[0][ntl] = MFMA16(A0, B, acc[0][ntl]);
            acc[1][ntl] = MFMA16(A1, B, acc[1][ntl]);
        }
    }
    // epilogue: h = gelu(g+bg)*(v+bv) -> hs
#pragma unroll
    for (int ntl = 0; ntl < 4; ntl++) {
        int colg = (w * 4 + ntl) * 16 + lg;
        float bg = bg1[colg], bv = bv1[colg];
#pragma unroll
        for (int mt = 0; mt < 2; mt++)
#pragma unroll
            for (int r = 0; r < 4; r++) {
                float g = acc[mt][ntl][r] + bg;
                float vv = acc[mt][ntl + 4][r] + bv;
                hs[mt * 16 + lq * 4 + r][colg] = __float2bfloat16(gelu_tanh(g) * vv);
            }
    }
    __syncthreads();

    // ---- GEMM2: h[32x256] @ Wo1 -> u; wave (m, nh): node m, col-tiles nh*4.. ----
    f4v acc2[4];
#pragma unroll
    for (int j = 0; j < 4; j++) acc2[j] = (f4v){0.f, 0.f, 0.f, 0.f};
    const bf16* Wto1 = wt + WTO1_OFS;
    for (int ko = 0; ko < 8; ko++) {
        bf8v A = *(const bf8v*)&hs[m * 16 + lg][ko * 32 + lq * 8];
#pragma unroll
        for (int nt = 0; nt < 4; nt++) {
            bf8v B = *(const bf8v*)(Wto1 + (size_t)((nh * 4 + nt) * 16 + lg) * HH + ko * 32 + lq * 8);
            acc2[nt] = MFMA16(A, B, acc2[nt]);
        }
    }
    // bias + LN partial over this wave's 64 cols
    float s[4] = {0, 0, 0, 0}, s2[4] = {0, 0, 0, 0};
#pragma unroll
    for (int nt = 0; nt < 4; nt++) {
        float bo = bo1[(nh * 4 + nt) * 16 + lg];
#pragma unroll
        for (int r = 0; r < 4; r++) {
            float u = acc2[nt][r] + bo;
            acc2[nt][r] = u;
            s[r] += u; s2[r] += u * u;
        }
    }
#pragma unroll
    for (int off = 1; off < 16; off <<= 1)
#pragma unroll
        for (int r = 0; r < 4; r++) {
            s[r]  += __shfl_xor(s[r], off, 64);
            s2[r] += __shfl_xor(s2[r], off, 64);
        }
    if (lg == 0)
#pragma unroll
        for (int r = 0; r < 4; r++) {
            lnp[nh][m * 16 + lq * 4 + r][0] = s[r];
            lnp[nh][m * 16 + lq * 4 + r][1] = s2[r];
        }
    __syncthreads();   // partials ready; all hs reads done -> pu may overwrite

    float mean[4], rstd[4];
#pragma unroll
    for (int r = 0; r < 4; r++) {
        int row = m * 16 + lq * 4 + r;
        float S  = lnp[0][row][0] + lnp[1][row][0];
        float S2 = lnp[0][row][1] + lnp[1][row][1];
        mean[r] = S * (1.0f / DD);
        float var = S2 * (1.0f / DD) - mean[r] * mean[r];
        rstd[r] = rsqrtf(var + 1e-5f);
    }

    const size_t OUT_PAIR_OFS = (size_t)NN * DD;
#pragma unroll
    for (int nt = 0; nt < 4; nt++) {
        int col = (nh * 4 + nt) * 16 + lg;
        float gpd = gp[col], bpd = bp[col];
#pragma unroll
        for (int r = 0; r < 4; r++) {
            int row = m * 16 + lq * 4 + r;
            float p = (acc2[nt][r] - mean[r]) * rstd[r] * gpd + bpd;
            pu[row][col] = p;
            size_t gidx = ((size_t)(n0 + m) * KK + (lq * 4 + r)) * DD + col;
            out[OUT_PAIR_OFS + gidx] = pairp[gidx] + p;
        }
    }
    __syncthreads();   // pu visible to gate waves

    // ---- Gates: pair[16x128] @ Win (nh=0) or Wout (nh=1) for node m ----
    f4v acc3[8];
#pragma unroll
    for (int j = 0; j < 8; j++) acc3[j] = (f4v){0.f, 0.f, 0.f, 0.f};
    const bf16* Wtg = wt + WTG_OFS;
    for (int ko = 0; ko < 4; ko++) {
        bf8v A = *(const bf8v*)&xs[m * 16 + lg][ko * 32 + lq * 8];  // pair cols
#pragma unroll
        for (int nt = 0; nt < 8; nt++) {
            bf8v B = *(const bf8v*)(Wtg + (size_t)((nh * 8 + nt) * 16 + lg) * DD + ko * 32 + lq * 8);
            acc3[nt] = MFMA16(A, B, acc3[nt]);
        }
    }
    if (nh == 0) {
        // incoming: sum_k sigm(gin)*pu*mask
#pragma unroll
        for (int nt = 0; nt < 8; nt++) {
            int col = nt * 16 + lg;
            float sl = 0.f;
#pragma unroll
            for (int r = 0; r < 4; r++) {
                int k = lq * 4 + r;
                sl += sigm(acc3[nt][r]) * pu[m * 16 + k][col] * msk_s[m * 16 + k];
            }
            sl += __shfl_xor(sl, 16, 64);
            sl += __shfl_xor(sl, 32, 64);
            if (l < 16)
                inc_ws[(size_t)(n0 + m) * DD + nt * 16 + l] = sl;
        }
    } else {
        // outgoing: scatter-add sigm(gout)*pu*mask to neighbour rows
#pragma unroll
        for (int nt = 0; nt < 8; nt++) {
            int col = nt * 16 + lg;
#pragma unroll
            for (int r = 0; r < 4; r++) {
                int k = lq * 4 + r;
                if (msk_s[m * 16 + k] != 0.0f) {
                    float o = sigm(acc3[nt][r]) * pu[m * 16 + k][col];
                    atomicAdd(&outg_ws[(size_t)nbr_s[m * 16 + k] * DD + col], o);
                }
            }
        }
    }
}

// One block = 16 nodes (M = 16 rows, 1 mtile). 1250 blocks. LDS ~21.5 KB.
__global__ __launch_bounds__(256, 4) void k_local(
    const float* __restrict__ localp, const float* __restrict__ inc_ws,
    const float* __restrict__ outg_ws, const bf16* __restrict__ wt,
    const float* __restrict__ bg2, const float* __restrict__ bv2,
    const float* __restrict__ bo2,
    const float* __restrict__ gl, const float* __restrict__ bl,
    float* __restrict__ out)
{
    __shared__ bf16 xs[16][392];           // 12544 B
    __shared__ char hs_raw[16 * 264 * 2];  // 8448 B
    __shared__ float lnp[4][16][2];        // 512 B
    bf16 (*hs)[264] = (bf16 (*)[264])hs_raw;

    const int t = threadIdx.x;
    const int n0 = blockIdx.x * 16;
    const int l = t & 63, w = t >> 6;
    const int lg = l & 15, lq = l >> 4;

    for (int idx = t; idx < 16 * 96; idx += 256) {
        int row = idx / 96, g = idx % 96, c = g * 4;
        size_t node = n0 + row;
        float4 v;
        if (c < 128)      v = *(const float4*)&localp[node * DD + c];
        else if (c < 256) v = *(const float4*)&inc_ws[node * DD + (c - 128)];
        else              v = *(const float4*)&outg_ws[node * DD + (c - 256)];
        bf16* dst = &xs[row][c];
        dst[0] = __float2bfloat16(v.x); dst[1] = __float2bfloat16(v.y);
        dst[2] = __float2bfloat16(v.z); dst[3] = __float2bfloat16(v.w);
    }
    __syncthreads();

    // GEMM1: [16x384] @ Wt2^T -> g|v [16x512]; wave w owns 4 g/v tile-pairs
    f4v acc[8];
#pragma unroll
    for (int j = 0; j < 8; j++) acc[j] = (f4v){0.f, 0.f, 0.f, 0.f};
    const bf16* Wt2 = wt + WT2_OFS;
    for (int ko = 0; ko < 12; ko++) {
        bf8v A = *(const bf8v*)&xs[lg][ko * 32 + lq * 8];
#pragma unroll
        for (int ntl = 0; ntl < 8; ntl++) {
            int nrow = (ntl < 4) ? (w * 4 + ntl) * 16 + lg
                                 : 256 + (w * 4 + (ntl - 4)) * 16 + lg;
            bf8v B = *(const bf8v*)(Wt2 + (size_t)nrow * IN3 + ko * 32 + lq * 8);
            acc[ntl] = MFMA16(A, B, acc[ntl]);
        }
    }
#pragma unroll
    for (int ntl = 0; ntl < 4; ntl++) {
        int colg = (w * 4 + ntl) * 16 + lg;
        float bg = bg2[colg], bv = bv2[colg];
#pragma unroll
        for (int r = 0; r < 4; r++) {
            float g = acc[ntl][r] + bg;
            float vv = acc[ntl + 4][r] + bv;
            hs[lq * 4 + r][colg] = __float2bfloat16(gelu_tanh(g) * vv);
        }
    }
    __syncthreads();

    // GEMM2: h[16x256] @ Wo2 -> u[16x128]; wave w owns col-tiles w*2, w*2+1
    f4v acc2[2];
#pragma unroll
    for (int j = 0; j < 2; j++) acc2[j] = (f4v){0.f, 0.f, 0.f, 0.f};
    const bf16* Wto2 = wt + WTO2_OFS;
    for (int ko = 0; ko < 8; ko++) {
        bf8v A = *(const bf8v*)&hs[lg][ko * 32 + lq * 8];
#pragma unroll
        for (int nt = 0; nt < 2; nt++) {
            bf8v B = *(const bf8v*)(Wto2 + (size_t)((w * 2 + nt) * 16 + lg) * HH + ko * 32 + lq * 8);
            acc2[nt] = MFMA16(A, B, acc2[nt]);
        }
    }
    float s[4] = {0, 0, 0, 0}, s2[4] = {0, 0, 0, 0};
#pragma unroll
    for (int nt = 0; nt < 2; nt++) {
        float bo = bo2[(w * 2 + nt) * 16 + lg];
#pragma unroll
        for (int r = 0; r < 4; r++) {
            float u = acc2[nt][r] + bo;
            acc2[nt][r] = u;
            s[r] += u; s2[r] += u * u;
        }
    }
#pragma unroll
    for (int off = 1; off < 16; off <<= 1)
#pragma unroll
        for (int r = 0; r < 4; r++) {
            s[r]  += __shfl_xor(s[r], off, 64);
            s2[r] += __shfl_xor(s2[r], off, 64);
        }
    if (lg == 0)
#pragma unroll
        for (int r = 0; r < 4; r++) {
            lnp[w][lq * 4 + r][0] = s[r];
            lnp[w][lq * 4 + r][1] = s2[r];
        }
    __syncthreads();

#pragma unroll
    for (int nt = 0; nt < 2; nt++) {
        int col = (w * 2 + nt) * 16 + lg;
        float gld = gl[col], bld = bl[col];
#pragma unroll
        for (int r = 0; r < 4; r++) {
            int row = lq * 4 + r;
            float S  = lnp[0][row][0] + lnp[1][row][0] + lnp[2][row][0] + lnp[3][row][0];
            float S2 = lnp[0][row][1] + lnp[1][row][1] + lnp[2][row][1] + lnp[3][row][1];
            float mean = S * (1.0f / DD);
            float var = S2 * (1.0f / DD) - mean * mean;
            float rstd = rsqrtf(var + 1e-5f);
            float p = (acc2[nt][r] - mean) * rstd * gld + bld;
            size_t node = n0 + row;
            out[node * DD + col] = localp[node * DD + col] + p;
        }
    }
}

extern "C" void kernel_launch(void* const* d_in, const int* in_sizes, int n_in,
                              void* d_out, int out_size, void* d_ws, size_t ws_size,
                              hipStream_t stream) {
    const float* local = (const float*)d_in[0];
    const float* pair  = (const float*)d_in[1];
    const int*   nbrs  = (const int*)d_in[2];
    const float* mask  = (const float*)d_in[3];
    const float* Wg1 = (const float*)d_in[4];
    const float* bg1 = (const float*)d_in[5];
    const float* Wv1 = (const float*)d_in[6];
    const float* bv1 = (const float*)d_in[7];
    const float* Wo1 = (const float*)d_in[8];
    const float* bo1 = (const float*)d_in[9];
    const float* gp  = (const float*)d_in[10];
    const float* bp  = (const float*)d_in[11];
    const float* Win = (const float*)d_in[12];
    const float* Wout= (const float*)d_in[13];
    const float* Wg2 = (const float*)d_in[14];
    const float* bg2 = (const float*)d_in[15];
    const float* Wv2 = (const float*)d_in[16];
    const float* bv2 = (const float*)d_in[17];
    const float* Wo2 = (const float*)d_in[18];
    const float* bo2 = (const float*)d_in[19];
    const float* gl  = (const float*)d_in[20];
    const float* bl  = (const float*)d_in[21];

    float* out = (float*)d_out;
    float* inc_ws  = (float*)d_ws;
    float* outg_ws = inc_ws + (size_t)NN * DD;
    bf16*  wt      = (bf16*)(outg_ws + (size_t)NN * DD);

    hipMemsetAsync(outg_ws, 0, (size_t)NN * DD * sizeof(float), stream);
    k_prep<<<(WT_TOTAL + 255) / 256, 256, 0, stream>>>(
        Wg1, Wv1, Wo1, Win, Wout, Wg2, Wv2, Wo2, wt);
    k_pair<<<NN / 2, 256, 0, stream>>>(local, pair, nbrs, mask, wt,
                                       bg1, bv1, bo1, gp, bp,
                                       out, inc_ws, outg_ws);
    k_local<<<NN / 16, 256, 0, stream>>>(local, inc_ws, outg_ws, wt,
                                         bg2, bv2, bo2, gl, bl, out);
}